// Round 16
// baseline (7569.321 us; speedup 1.0000x reference)
//
#include <hip/hip_runtime.h>
#include <hip/hip_bf16.h>

#define SEQ 512
#define HD 1024
#define NWG 256
#define TPB 512
#define RED_OFF 131072
#define LDS_BYTES (131072 + 32768)
#define OUT_H 33554432ull
#define OUT_C 33619968ull
#define RMASK 31
#define HSLOT 131072   // shorts per h ring slot: 64 b x 2048 (packed hi|lo per 32-chunk)

typedef __bf16 bf16x8 __attribute__((ext_vector_type(8)));
typedef float f32x4 __attribute__((ext_vector_type(4)));

__device__ __forceinline__ unsigned short f2bf(float f) {
  __hip_bfloat16 b = __float2bfloat16(f);  // RNE
  return __builtin_bit_cast(unsigned short, b);
}
__device__ __forceinline__ float bf2f(unsigned short s) {
  return __builtin_bit_cast(float, (unsigned)s << 16);
}

__device__ __forceinline__ float sigm(float v) { return 1.f / (1.f + __expf(-v)); }
__device__ __forceinline__ float tanh_(float v) {
  float av = fabsf(v);
  float e = __expf(-2.f * av);
  float t = (1.f - e) / (1.f + e);
  return copysignf(t, v);
}

__device__ __forceinline__ void gl2lds(const void* g, void* l) {
  __builtin_amdgcn_global_load_lds(
      (const __attribute__((address_space(1))) void*)g,
      (__attribute__((address_space(3))) void*)l, 16, 0, 0);
}

// Round-16 notify: per-step monotone counter ring (64 slots/layer, one 128B
// line each). Writer: relaxed fetch_add(+1) on slot T&63 after drain+R2.
// "Layer finished step T" <=> slot[T&63] >= 128*((T>>6)+1). Per-slot targets
// are sound under the existing skew bounds (<64: intra-layer <=1, cross <=32)
// -- a single monotone sum-counter would NOT be (runaway-sum hazard).
__device__ __forceinline__ void wait_step(const unsigned* cbase, int T) {
  const unsigned* p = cbase + ((unsigned)(T & 63) << 5);
  const unsigned tgt = 128u * (unsigned)((T >> 6) + 1);
  while (__hip_atomic_load(p, __ATOMIC_RELAXED, __HIP_MEMORY_SCOPE_AGENT) < tgt)
    __builtin_amdgcn_s_sleep(1);
  __builtin_amdgcn_wave_barrier();
  asm volatile("" ::: "memory");
}

// Persistent LSTM, round-16: r15 core (8 waves, K-split 8, K-32 staging steps,
// packed h [b][chunk][hi32|lo32], 2-round tree + 4-wave finish) with the
// leader-gather/go-publish notify replaced by the counter ring (1 hop less).
__global__ __launch_bounds__(TPB, 2) void lstm_main(
    const float* __restrict__ x,
    const float* __restrict__ Wih_f,
    const float* __restrict__ Whh_f,
    const float* __restrict__ bias,
    unsigned short* h0p, unsigned short* h1p,
    float* __restrict__ out,
    unsigned* bar) {
  __shared__ char smem[LDS_BYTES];
  float* red = (float*)(smem + RED_OFF);

  unsigned* c0 = bar;           // L0 counter ring: 64 slots x 32 words
  unsigned* c1 = bar + 2048;    // L1 counter ring

  const int w = blockIdx.x;
  const int tid = threadIdx.x;
  const int layer = w >> 7;
  const int tl = w & 127;
  const int j0 = tl << 3;
  const int lane = tid & 63;
  const int kw = tid >> 6;            // 0..7, K-slice of 256
  const int cl = lane & 15;
  const int rg = lane >> 4;
  const int kbase = kw << 8;
  const bool isx = (layer == 0) && (kw < 4);

  // ---- W prologue: hi+lo fragments, 8 ks-chunks x 2 nt = 16 uint4 each
  uint4 whi[16], wlo[16];
#pragma unroll
  for (int i = 0; i < 16; ++i) {
    const int nt = i & 1, ks = i >> 1;
    const int c = nt * 16 + cl;
    const int grow = ((c >> 3) << 10) + j0 + (c & 7);
    const int kglob = kbase + (ks << 5) + (rg << 3);
    const float* src = (kglob < HD)
        ? (Wih_f + (((size_t)layer << 22) + ((size_t)grow << 10) + kglob))
        : (Whh_f + (((size_t)layer << 22) + ((size_t)grow << 10) + (kglob - HD)));
    union { unsigned short s2[8]; uint4 v; } uh, ul;
#pragma unroll
    for (int e = 0; e < 8; ++e) {
      const float vv = src[e];
      const unsigned short hb = f2bf(vv);
      uh.s2[e] = hb;
      ul.s2[e] = f2bf(vv - bf2f(hb));
    }
    whi[i] = uh.v;
    wlo[i] = ul.v;
  }

  const int u_ = cl & 7;
  const float bi  = bias[(layer << 12) + j0 + u_];
  const float bf_ = bias[(layer << 12) + 1024 + j0 + u_];
  const float bg  = bias[(layer << 12) + 2048 + j0 + u_];
  const float bo  = bias[(layer << 12) + 3072 + j0 + u_];

  float creg[4];
#pragma unroll
  for (int i = 0; i < 4; ++i) creg[i] = 0.f;

  char* sbase = smem + (kw << 14);    // 16KB/wave: 2 x 8KB step buffers
  const int srow = lane >> 3;         // staging row-in-group 0..7
  const int sslot = (lane & 7) ^ srow;// pre-swizzled source slot (16B units)
  const int hkc = (kw & 3) << 3;      // h chunk base (8 chunks per wave)

  __syncthreads();

  for (int t = 0; t < SEQ; ++t) {
    // ---- per-wave gating via counter ring (L0 x-waves: none)
    if (layer == 0) {
      if (kw >= 4 && t >= 1) wait_step(c0, t - 1);   // h0[t-1] published
    } else {
      if (kw < 4) wait_step(c0, t);                  // h0[t] published
      else if (t >= 1) wait_step(c1, t - 1);         // h1[t-1] published
    }

    f32x4 acc[4][2];
#pragma unroll
    for (int mt = 0; mt < 4; ++mt) {
      acc[mt][0] = (f32x4){0.f, 0.f, 0.f, 0.f};
      acc[mt][1] = (f32x4){0.f, 0.f, 0.f, 0.f};
    }

    if (isx) {
      // ---- x path: K-32 steps; row = 128B (32 fp32) full-line coalesced
      const float* xb = x + ((size_t)(srow * SEQ + t) << 10) + kbase + (sslot << 2);
#pragma unroll
      for (int i = 0; i < 8; ++i)
        gl2lds(xb + (size_t)i * 4194304, sbase + (i << 10));
#pragma unroll
      for (int s = 0; s < 8; ++s) {
        char* cb = sbase + ((s & 1) << 13);
        if (s < 7) {
          char* nb = sbase + (((s + 1) & 1) << 13);
#pragma unroll
          for (int i = 0; i < 8; ++i)
            gl2lds(xb + (size_t)i * 4194304 + ((s + 1) << 5), nb + (i << 10));
          asm volatile("s_waitcnt vmcnt(8)" ::: "memory");
        } else {
          asm volatile("s_waitcnt vmcnt(0)" ::: "memory");
        }
        const bf16x8 bh0 = __builtin_bit_cast(bf16x8, whi[(s << 1)]);
        const bf16x8 bh1 = __builtin_bit_cast(bf16x8, whi[(s << 1) + 1]);
        const bf16x8 bl0 = __builtin_bit_cast(bf16x8, wlo[(s << 1)]);
        const bf16x8 bl1 = __builtin_bit_cast(bf16x8, wlo[(s << 1) + 1]);
#pragma unroll
        for (int mt = 0; mt < 4; ++mt) {
          const int row = (mt << 4) + cl;
          const int wv = row & 7;
          const char* rb = cb + ((row >> 3) << 10) + (wv << 7);
          const float4 f0 = *(const float4*)(rb + (((rg << 1) ^ wv) << 4));
          const float4 f1 = *(const float4*)(rb + ((((rg << 1) | 1) ^ wv) << 4));
          union { unsigned short s2[8]; uint4 v; } uh, ul;
          const float ee[8] = {f0.x, f0.y, f0.z, f0.w, f1.x, f1.y, f1.z, f1.w};
#pragma unroll
          for (int e2 = 0; e2 < 8; ++e2) {
            const unsigned uu = __builtin_bit_cast(unsigned, ee[e2]);
            uh.s2[e2] = (unsigned short)(uu >> 16);
            ul.s2[e2] = f2bf(ee[e2] - __builtin_bit_cast(float, uu & 0xffff0000u));
          }
          const bf16x8 ah = __builtin_bit_cast(bf16x8, uh.v);
          const bf16x8 al = __builtin_bit_cast(bf16x8, ul.v);
          acc[mt][0] = __builtin_amdgcn_mfma_f32_16x16x32_bf16(ah, bh0, acc[mt][0], 0, 0, 0);
          acc[mt][1] = __builtin_amdgcn_mfma_f32_16x16x32_bf16(ah, bh1, acc[mt][1], 0, 0, 0);
          acc[mt][0] = __builtin_amdgcn_mfma_f32_16x16x32_bf16(al, bh0, acc[mt][0], 0, 0, 0);
          acc[mt][1] = __builtin_amdgcn_mfma_f32_16x16x32_bf16(al, bh1, acc[mt][1], 0, 0, 0);
          acc[mt][0] = __builtin_amdgcn_mfma_f32_16x16x32_bf16(ah, bl0, acc[mt][0], 0, 0, 0);
          acc[mt][1] = __builtin_amdgcn_mfma_f32_16x16x32_bf16(ah, bl1, acc[mt][1], 0, 0, 0);
        }
      }
    } else {
      // ---- h path: packed [b][chunk][hi32|lo32]; row = 128B full-line
      const unsigned short* hsl;
      if (layer == 0)  hsl = h0p + (size_t)((t - 1) & RMASK) * HSLOT;
      else if (kw < 4) hsl = h0p + (size_t)(t & RMASK) * HSLOT;
      else             hsl = h1p + (size_t)((t - 1) & RMASK) * HSLOT;
      const unsigned short* hb = hsl + (srow << 11) + (hkc << 6) + (sslot << 3);
#pragma unroll
      for (int i = 0; i < 8; ++i)
        gl2lds(hb + (i << 14), sbase + (i << 10));
#pragma unroll
      for (int s = 0; s < 8; ++s) {
        char* cb = sbase + ((s & 1) << 13);
        if (s < 7) {
          char* nb = sbase + (((s + 1) & 1) << 13);
#pragma unroll
          for (int i = 0; i < 8; ++i)
            gl2lds(hb + (i << 14) + ((s + 1) << 6), nb + (i << 10));
          asm volatile("s_waitcnt vmcnt(8)" ::: "memory");
        } else {
          asm volatile("s_waitcnt vmcnt(0)" ::: "memory");
        }
        const bf16x8 bh0 = __builtin_bit_cast(bf16x8, whi[(s << 1)]);
        const bf16x8 bh1 = __builtin_bit_cast(bf16x8, whi[(s << 1) + 1]);
        const bf16x8 bl0 = __builtin_bit_cast(bf16x8, wlo[(s << 1)]);
        const bf16x8 bl1 = __builtin_bit_cast(bf16x8, wlo[(s << 1) + 1]);
#pragma unroll
        for (int mt = 0; mt < 4; ++mt) {
          const int row = (mt << 4) + cl;
          const int wv = row & 7;
          const char* rb = cb + ((row >> 3) << 10) + (wv << 7);
          const bf16x8 ah = __builtin_bit_cast(bf16x8, *(const uint4*)(rb + ((rg ^ wv) << 4)));
          const bf16x8 al = __builtin_bit_cast(bf16x8, *(const uint4*)(rb + (((4 | rg) ^ wv) << 4)));
          acc[mt][0] = __builtin_amdgcn_mfma_f32_16x16x32_bf16(ah, bh0, acc[mt][0], 0, 0, 0);
          acc[mt][1] = __builtin_amdgcn_mfma_f32_16x16x32_bf16(ah, bh1, acc[mt][1], 0, 0, 0);
          acc[mt][0] = __builtin_amdgcn_mfma_f32_16x16x32_bf16(al, bh0, acc[mt][0], 0, 0, 0);
          acc[mt][1] = __builtin_amdgcn_mfma_f32_16x16x32_bf16(al, bh1, acc[mt][1], 0, 0, 0);
          acc[mt][0] = __builtin_amdgcn_mfma_f32_16x16x32_bf16(ah, bl0, acc[mt][0], 0, 0, 0);
          acc[mt][1] = __builtin_amdgcn_mfma_f32_16x16x32_bf16(ah, bl1, acc[mt][1], 0, 0, 0);
        }
      }
    }

    // ---- 2-round tree reduction (4 slots x 8KB = 32KB)
    if (kw >= 4) {
      float* rp = red + ((kw - 4) << 11) + lane;
#pragma unroll
      for (int mt = 0; mt < 4; ++mt)
#pragma unroll
        for (int nt = 0; nt < 2; ++nt)
#pragma unroll
          for (int r = 0; r < 4; ++r)
            rp[((mt << 3) + (nt << 2) + r) << 6] = acc[mt][nt][r];
    }
    __syncthreads();  // B: round-1 dumps visible
    if (kw < 4) {
      float* rp = red + (kw << 11) + lane;
#pragma unroll
      for (int mt = 0; mt < 4; ++mt)
#pragma unroll
        for (int nt = 0; nt < 2; ++nt)
#pragma unroll
          for (int r = 0; r < 4; ++r) {
            const int idx = ((mt << 3) + (nt << 2) + r) << 6;
            acc[mt][nt][r] += rp[idx];   // P = S_kw + S_{kw+4}
            rp[idx] = acc[mt][nt][r];
          }
    }
    __syncthreads();  // C: partials visible

    float hsv[4] = {0.f, 0.f, 0.f, 0.f}, csv[4] = {0.f, 0.f, 0.f, 0.f};
    if (kw < 4) {
      // finisher wave kw: row-tile mt=kw; sum = P0+P1+P2+P3 (deterministic)
      float g0[4], g1[4];
#pragma unroll
      for (int r = 0; r < 4; ++r) {
        const int i0x = (((kw << 3) + r) << 6) + lane;
        const int i1x = (((kw << 3) + 4 + r) << 6) + lane;
        g0[r] = red[i0x] + red[2048 + i0x] + red[4096 + i0x] + red[6144 + i0x];
        g1[r] = red[i1x] + red[2048 + i1x] + red[4096 + i1x] + red[6144 + i1x];
      }
      // ring guard: L1 must have finished t-32 before slot t&31 is overwritten
      if (layer == 0 && t >= 32) wait_step(c1, t - 32);
      const int wsl = t & RMASK;
      unsigned short* hd = (layer ? h1p : h0p) + (size_t)wsl * HSLOT;
      const int ch = tl >> 2;
      const int cpos = ((tl & 3) << 3) + u_;
#pragma unroll
      for (int r = 0; r < 4; ++r) {
        const float a0 = g0[r], a1 = g1[r];
        const float a0x = __shfl_xor(a0, 8);
        const float a1x = __shfl_xor(a1, 8);
        const bool lo = (cl < 8);
        const float vi = (lo ? a0 : a0x) + bi;
        const float vf = (lo ? a0x : a0) + bf_;
        const float vg = (lo ? a1 : a1x) + bg;
        const float vo = (lo ? a1x : a1) + bo;
        const float ig = sigm(vi), fg = sigm(vf), gg = tanh_(vg), og = sigm(vo);
        const float cn = fg * creg[r] + ig * gg;
        creg[r] = cn;
        const float h = og * tanh_(cn);
        hsv[r] = h; csv[r] = cn;
        if (lo) {
          const int b = (kw << 4) + (rg << 2) + r;
          const size_t hx = ((size_t)b << 11) + (ch << 6) + cpos;
          const unsigned short hb16 = f2bf(h);
          const unsigned short lb16 = f2bf(h - bf2f(hb16));
          __hip_atomic_store(hd + hx, hb16, __ATOMIC_RELAXED, __HIP_MEMORY_SCOPE_AGENT);
          __hip_atomic_store(hd + hx + 32, lb16, __ATOMIC_RELAXED, __HIP_MEMORY_SCOPE_AGENT);
        }
      }
      asm volatile("s_waitcnt vmcnt(0)" ::: "memory");  // drain h publishes
    }
    __syncthreads();  // R2: publishes drained; red free for t+1

    // ---- notify: one relaxed add on this layer's counter slot (no leader)
    if (tid == 0) {
      unsigned* slot = (layer ? c1 : c0) + ((unsigned)(t & 63) << 5);
      (void)__hip_atomic_fetch_add(slot, 1u, __ATOMIC_RELAXED, __HIP_MEMORY_SCOPE_AGENT);
    }

    // deferred out stores (finishers of layer 1; never read back)
    if (layer && kw < 4 && cl < 8) {
#pragma unroll
      for (int r = 0; r < 4; ++r) {
        const int b = (kw << 4) + (rg << 2) + r;
        out[((size_t)b * SEQ + t) * HD + j0 + u_] = hsv[r];
        if (t == SEQ - 1) {
          out[OUT_H + (size_t)(b << 10) + j0 + u_] = hsv[r];
          out[OUT_C + (size_t)(b << 10) + j0 + u_] = csv[r];
        }
      }
    }

    if ((t & 15) == 15) __builtin_amdgcn_fence(__ATOMIC_ACQUIRE, "agent");
  }
}

// prep: combined bias, zero h-ring slot 31 (both packed buffers), counters
__global__ void lstm_prep(const float* __restrict__ bih, const float* __restrict__ bhh,
                          float* __restrict__ bias,
                          unsigned short* __restrict__ h0p, unsigned short* __restrict__ h1p,
                          unsigned* __restrict__ bar) {
  const size_t i0 = (size_t)blockIdx.x * blockDim.x + threadIdx.x;
  const size_t stride = (size_t)gridDim.x * blockDim.x;
  for (size_t idx = i0; idx < 8192; idx += stride) bias[idx] = bih[idx] + bhh[idx];
  const ushort4 z = make_ushort4(0, 0, 0, 0);
  const size_t so = ((size_t)RMASK * HSLOT) >> 2;  // slot 31 base, ushort4 units
  for (size_t idx = i0; idx < 32768; idx += stride) {
    ((ushort4*)h0p)[so + idx] = z;
    ((ushort4*)h1p)[so + idx] = z;
  }
  for (size_t idx = i0; idx < 8256; idx += stride) bar[idx] = 0u;  // counter rings
}

extern "C" void kernel_launch(void* const* d_in, const int* in_sizes, int n_in,
                              void* d_out, int out_size, void* d_ws, size_t ws_size,
                              hipStream_t stream) {
  const float* x     = (const float*)d_in[0];
  const float* Wih_f = (const float*)d_in[1];
  const float* bih   = (const float*)d_in[2];
  const float* Whh_f = (const float*)d_in[3];
  const float* bhh   = (const float*)d_in[4];
  float* out = (float*)d_out;

  char* ws = (char*)d_ws;                                  // ~17 MB used
  float* bias           = (float*)(ws);                    // 32 KB
  unsigned* bar         = (unsigned*)(ws + 65536);         // counter rings (33 KB)
  unsigned short* h0p   = (unsigned short*)(ws + (1ull << 20));            // 8 MB
  unsigned short* h1p   = (unsigned short*)(ws + (1ull << 20) + (8ull << 20)); // 8 MB

  hipLaunchKernelGGL(lstm_prep, dim3(256), dim3(256), 0, stream,
                     bih, bhh, bias, h0p, h1p, bar);

  hipLaunchKernelGGL(lstm_main, dim3(NWG), dim3(TPB), 0, stream,
                     x, Wih_f, Whh_f, bias, h0p, h1p, out, bar);
}

// Round 17
// 6312.502 us; speedup vs baseline: 1.1991x; 1.1991x over previous
//
#include <hip/hip_runtime.h>
#include <hip/hip_bf16.h>

#define SEQ 512
#define HD 1024
#define NWG 256
#define TPB 512
#define RED_OFF 131072
#define LDS_BYTES (131072 + 32768)
#define OUT_H 33554432ull
#define OUT_C 33619968ull
#define RMASK 31
#define HSLOT 131072   // shorts per h ring slot: 64 b x 2048 (packed hi|lo per 32-chunk)

typedef __bf16 bf16x8 __attribute__((ext_vector_type(8)));
typedef float f32x4 __attribute__((ext_vector_type(4)));

__device__ __forceinline__ unsigned short f2bf(float f) {
  __hip_bfloat16 b = __float2bfloat16(f);  // RNE
  return __builtin_bit_cast(unsigned short, b);
}
__device__ __forceinline__ float bf2f(unsigned short s) {
  return __builtin_bit_cast(float, (unsigned)s << 16);
}

__device__ __forceinline__ float sigm(float v) { return 1.f / (1.f + __expf(-v)); }
__device__ __forceinline__ float tanh_(float v) {
  float av = fabsf(v);
  float e = __expf(-2.f * av);
  float t = (1.f - e) / (1.f + e);
  return copysignf(t, v);
}

__device__ __forceinline__ void gl2lds(const void* g, void* l) {
  __builtin_amdgcn_global_load_lds(
      (const __attribute__((address_space(1))) void*)g,
      (__attribute__((address_space(3))) void*)l, 16, 0, 0);
}

__device__ __forceinline__ void wave_wait_ge(const unsigned* a, unsigned v) {
  while (__hip_atomic_load(a, __ATOMIC_RELAXED, __HIP_MEMORY_SCOPE_AGENT) < v)
    __builtin_amdgcn_s_sleep(1);
  __builtin_amdgcn_wave_barrier();
  asm volatile("" ::: "memory");
}

// Round-17: r15 core verbatim (8 waves 2/SIMD, K-split 8, K-32 staging steps,
// packed h [b][chunk][hi32|lo32], 2-round tree + 4-wave finish, leader gather
// + go publish) with PER-WAVE EARLY FLAGS: each finisher wave posts its own
// flag word (4 per WG line) right after its private vmcnt(0) drain, BEFORE R2.
// r16 lesson applied: parallel flag lines, no shared atomic RMW on the path.
__global__ __launch_bounds__(TPB, 2) void lstm_main(
    const float* __restrict__ x,
    const float* __restrict__ Wih_f,
    const float* __restrict__ Whh_f,
    const float* __restrict__ bias,
    unsigned short* h0p, unsigned short* h1p,
    float* __restrict__ out,
    unsigned* bar) {
  __shared__ char smem[LDS_BYTES];
  float* red = (float*)(smem + RED_OFF);

  unsigned* go0 = bar + 8192;
  unsigned* go1 = bar + 8192 + 32;

  const int w = blockIdx.x;
  const int tid = threadIdx.x;
  const int layer = w >> 7;
  const int tl = w & 127;
  const int j0 = tl << 3;
  const int lane = tid & 63;
  const int kw = tid >> 6;            // 0..7, K-slice of 256
  const int cl = lane & 15;
  const int rg = lane >> 4;
  const int kbase = kw << 8;
  const bool isx = (layer == 0) && (kw < 4);

  // ---- W prologue: hi+lo fragments, 8 ks-chunks x 2 nt = 16 uint4 each
  uint4 whi[16], wlo[16];
#pragma unroll
  for (int i = 0; i < 16; ++i) {
    const int nt = i & 1, ks = i >> 1;
    const int c = nt * 16 + cl;
    const int grow = ((c >> 3) << 10) + j0 + (c & 7);
    const int kglob = kbase + (ks << 5) + (rg << 3);
    const float* src = (kglob < HD)
        ? (Wih_f + (((size_t)layer << 22) + ((size_t)grow << 10) + kglob))
        : (Whh_f + (((size_t)layer << 22) + ((size_t)grow << 10) + (kglob - HD)));
    union { unsigned short s2[8]; uint4 v; } uh, ul;
#pragma unroll
    for (int e = 0; e < 8; ++e) {
      const float vv = src[e];
      const unsigned short hb = f2bf(vv);
      uh.s2[e] = hb;
      ul.s2[e] = f2bf(vv - bf2f(hb));
    }
    whi[i] = uh.v;
    wlo[i] = ul.v;
  }

  const int u_ = cl & 7;
  const float bi  = bias[(layer << 12) + j0 + u_];
  const float bf_ = bias[(layer << 12) + 1024 + j0 + u_];
  const float bg  = bias[(layer << 12) + 2048 + j0 + u_];
  const float bo  = bias[(layer << 12) + 3072 + j0 + u_];

  float creg[4];
#pragma unroll
  for (int i = 0; i < 4; ++i) creg[i] = 0.f;

  char* sbase = smem + (kw << 14);    // 16KB/wave: 2 x 8KB step buffers
  const int srow = lane >> 3;         // staging row-in-group 0..7
  const int sslot = (lane & 7) ^ srow;// pre-swizzled source slot (16B units)
  const int hkc = (kw & 3) << 3;      // h chunk base (8 chunks per wave)

  __syncthreads();

  for (int t = 0; t < SEQ; ++t) {
    const unsigned e = (unsigned)(t + 1);

    if (layer == 0) {
      if (kw >= 4) wave_wait_ge(go0, (unsigned)t);          // h0[t-1]
    } else {
      if (kw < 4) wave_wait_ge(go0, e);                     // h0[t]
      else        wave_wait_ge(go1, (unsigned)t);           // h1[t-1]
    }

    f32x4 acc[4][2];
#pragma unroll
    for (int mt = 0; mt < 4; ++mt) {
      acc[mt][0] = (f32x4){0.f, 0.f, 0.f, 0.f};
      acc[mt][1] = (f32x4){0.f, 0.f, 0.f, 0.f};
    }

    if (isx) {
      // ---- x path: K-32 steps; row = 128B (32 fp32) full-line coalesced
      const float* xb = x + ((size_t)(srow * SEQ + t) << 10) + kbase + (sslot << 2);
#pragma unroll
      for (int i = 0; i < 8; ++i)
        gl2lds(xb + (size_t)i * 4194304, sbase + (i << 10));
#pragma unroll
      for (int s = 0; s < 8; ++s) {
        char* cb = sbase + ((s & 1) << 13);
        if (s < 7) {
          char* nb = sbase + (((s + 1) & 1) << 13);
#pragma unroll
          for (int i = 0; i < 8; ++i)
            gl2lds(xb + (size_t)i * 4194304 + ((s + 1) << 5), nb + (i << 10));
          asm volatile("s_waitcnt vmcnt(8)" ::: "memory");
        } else {
          asm volatile("s_waitcnt vmcnt(0)" ::: "memory");
        }
        const bf16x8 bh0 = __builtin_bit_cast(bf16x8, whi[(s << 1)]);
        const bf16x8 bh1 = __builtin_bit_cast(bf16x8, whi[(s << 1) + 1]);
        const bf16x8 bl0 = __builtin_bit_cast(bf16x8, wlo[(s << 1)]);
        const bf16x8 bl1 = __builtin_bit_cast(bf16x8, wlo[(s << 1) + 1]);
#pragma unroll
        for (int mt = 0; mt < 4; ++mt) {
          const int row = (mt << 4) + cl;
          const int wv = row & 7;
          const char* rb = cb + ((row >> 3) << 10) + (wv << 7);
          const float4 f0 = *(const float4*)(rb + (((rg << 1) ^ wv) << 4));
          const float4 f1 = *(const float4*)(rb + ((((rg << 1) | 1) ^ wv) << 4));
          union { unsigned short s2[8]; uint4 v; } uh, ul;
          const float ee[8] = {f0.x, f0.y, f0.z, f0.w, f1.x, f1.y, f1.z, f1.w};
#pragma unroll
          for (int e2 = 0; e2 < 8; ++e2) {
            const unsigned uu = __builtin_bit_cast(unsigned, ee[e2]);
            uh.s2[e2] = (unsigned short)(uu >> 16);
            ul.s2[e2] = f2bf(ee[e2] - __builtin_bit_cast(float, uu & 0xffff0000u));
          }
          const bf16x8 ah = __builtin_bit_cast(bf16x8, uh.v);
          const bf16x8 al = __builtin_bit_cast(bf16x8, ul.v);
          acc[mt][0] = __builtin_amdgcn_mfma_f32_16x16x32_bf16(ah, bh0, acc[mt][0], 0, 0, 0);
          acc[mt][1] = __builtin_amdgcn_mfma_f32_16x16x32_bf16(ah, bh1, acc[mt][1], 0, 0, 0);
          acc[mt][0] = __builtin_amdgcn_mfma_f32_16x16x32_bf16(al, bh0, acc[mt][0], 0, 0, 0);
          acc[mt][1] = __builtin_amdgcn_mfma_f32_16x16x32_bf16(al, bh1, acc[mt][1], 0, 0, 0);
          acc[mt][0] = __builtin_amdgcn_mfma_f32_16x16x32_bf16(ah, bl0, acc[mt][0], 0, 0, 0);
          acc[mt][1] = __builtin_amdgcn_mfma_f32_16x16x32_bf16(ah, bl1, acc[mt][1], 0, 0, 0);
        }
      }
    } else {
      // ---- h path: packed [b][chunk][hi32|lo32]; row = 128B full-line
      const unsigned short* hsl;
      if (layer == 0)  hsl = h0p + (size_t)((t - 1) & RMASK) * HSLOT;
      else if (kw < 4) hsl = h0p + (size_t)(t & RMASK) * HSLOT;
      else             hsl = h1p + (size_t)((t - 1) & RMASK) * HSLOT;
      const unsigned short* hb = hsl + (srow << 11) + (hkc << 6) + (sslot << 3);
#pragma unroll
      for (int i = 0; i < 8; ++i)
        gl2lds(hb + (i << 14), sbase + (i << 10));
#pragma unroll
      for (int s = 0; s < 8; ++s) {
        char* cb = sbase + ((s & 1) << 13);
        if (s < 7) {
          char* nb = sbase + (((s + 1) & 1) << 13);
#pragma unroll
          for (int i = 0; i < 8; ++i)
            gl2lds(hb + (i << 14) + ((s + 1) << 6), nb + (i << 10));
          asm volatile("s_waitcnt vmcnt(8)" ::: "memory");
        } else {
          asm volatile("s_waitcnt vmcnt(0)" ::: "memory");
        }
        const bf16x8 bh0 = __builtin_bit_cast(bf16x8, whi[(s << 1)]);
        const bf16x8 bh1 = __builtin_bit_cast(bf16x8, whi[(s << 1) + 1]);
        const bf16x8 bl0 = __builtin_bit_cast(bf16x8, wlo[(s << 1)]);
        const bf16x8 bl1 = __builtin_bit_cast(bf16x8, wlo[(s << 1) + 1]);
#pragma unroll
        for (int mt = 0; mt < 4; ++mt) {
          const int row = (mt << 4) + cl;
          const int wv = row & 7;
          const char* rb = cb + ((row >> 3) << 10) + (wv << 7);
          const bf16x8 ah = __builtin_bit_cast(bf16x8, *(const uint4*)(rb + ((rg ^ wv) << 4)));
          const bf16x8 al = __builtin_bit_cast(bf16x8, *(const uint4*)(rb + (((4 | rg) ^ wv) << 4)));
          acc[mt][0] = __builtin_amdgcn_mfma_f32_16x16x32_bf16(ah, bh0, acc[mt][0], 0, 0, 0);
          acc[mt][1] = __builtin_amdgcn_mfma_f32_16x16x32_bf16(ah, bh1, acc[mt][1], 0, 0, 0);
          acc[mt][0] = __builtin_amdgcn_mfma_f32_16x16x32_bf16(al, bh0, acc[mt][0], 0, 0, 0);
          acc[mt][1] = __builtin_amdgcn_mfma_f32_16x16x32_bf16(al, bh1, acc[mt][1], 0, 0, 0);
          acc[mt][0] = __builtin_amdgcn_mfma_f32_16x16x32_bf16(ah, bl0, acc[mt][0], 0, 0, 0);
          acc[mt][1] = __builtin_amdgcn_mfma_f32_16x16x32_bf16(ah, bl1, acc[mt][1], 0, 0, 0);
        }
      }
    }

    // ---- 2-round tree reduction (4 slots x 8KB = 32KB)
    if (kw >= 4) {
      float* rp = red + ((kw - 4) << 11) + lane;
#pragma unroll
      for (int mt = 0; mt < 4; ++mt)
#pragma unroll
        for (int nt = 0; nt < 2; ++nt)
#pragma unroll
          for (int r = 0; r < 4; ++r)
            rp[((mt << 3) + (nt << 2) + r) << 6] = acc[mt][nt][r];
    }
    __syncthreads();  // B: round-1 dumps visible
    if (kw < 4) {
      float* rp = red + (kw << 11) + lane;
#pragma unroll
      for (int mt = 0; mt < 4; ++mt)
#pragma unroll
        for (int nt = 0; nt < 2; ++nt)
#pragma unroll
          for (int r = 0; r < 4; ++r) {
            const int idx = ((mt << 3) + (nt << 2) + r) << 6;
            acc[mt][nt][r] += rp[idx];   // P = S_kw + S_{kw+4}
            rp[idx] = acc[mt][nt][r];
          }
    }
    __syncthreads();  // C: partials visible

    float hsv[4] = {0.f, 0.f, 0.f, 0.f}, csv[4] = {0.f, 0.f, 0.f, 0.f};
    if (kw < 4) {
      // finisher wave kw: row-tile mt=kw; sum = P0+P1+P2+P3 (deterministic)
      float g0[4], g1[4];
#pragma unroll
      for (int r = 0; r < 4; ++r) {
        const int i0x = (((kw << 3) + r) << 6) + lane;
        const int i1x = (((kw << 3) + 4 + r) << 6) + lane;
        g0[r] = red[i0x] + red[2048 + i0x] + red[4096 + i0x] + red[6144 + i0x];
        g1[r] = red[i1x] + red[2048 + i1x] + red[4096 + i1x] + red[6144 + i1x];
      }
      if (layer == 0 && t >= 32) wave_wait_ge(go1, (unsigned)(t - 31));
      const int wsl = t & RMASK;
      unsigned short* hd = (layer ? h1p : h0p) + (size_t)wsl * HSLOT;
      const int ch = tl >> 2;
      const int cpos = ((tl & 3) << 3) + u_;
#pragma unroll
      for (int r = 0; r < 4; ++r) {
        const float a0 = g0[r], a1 = g1[r];
        const float a0x = __shfl_xor(a0, 8);
        const float a1x = __shfl_xor(a1, 8);
        const bool lo = (cl < 8);
        const float vi = (lo ? a0 : a0x) + bi;
        const float vf = (lo ? a0x : a0) + bf_;
        const float vg = (lo ? a1 : a1x) + bg;
        const float vo = (lo ? a1x : a1) + bo;
        const float ig = sigm(vi), fg = sigm(vf), gg = tanh_(vg), og = sigm(vo);
        const float cn = fg * creg[r] + ig * gg;
        creg[r] = cn;
        const float h = og * tanh_(cn);
        hsv[r] = h; csv[r] = cn;
        if (lo) {
          const int b = (kw << 4) + (rg << 2) + r;
          const size_t hx = ((size_t)b << 11) + (ch << 6) + cpos;
          const unsigned short hb16 = f2bf(h);
          const unsigned short lb16 = f2bf(h - bf2f(hb16));
          __hip_atomic_store(hd + hx, hb16, __ATOMIC_RELAXED, __HIP_MEMORY_SCOPE_AGENT);
          __hip_atomic_store(hd + hx + 32, lb16, __ATOMIC_RELAXED, __HIP_MEMORY_SCOPE_AGENT);
        }
      }
      asm volatile("s_waitcnt vmcnt(0)" ::: "memory");  // drain own h publishes
      // ---- EARLY per-wave flag: this finisher's h is L3-visible; post now,
      // before R2 (4 words per WG line; leader checks all 4).
      if (lane == 0)
        __hip_atomic_store(bar + (w << 5) + kw, e, __ATOMIC_RELAXED, __HIP_MEMORY_SCOPE_AGENT);
    }
    __syncthreads();  // R2: red free for t+1 (flags already posted)

    // deferred out stores (finishers of layer 1; never read back)
    if (layer && kw < 4 && cl < 8) {
#pragma unroll
      for (int r = 0; r < 4; ++r) {
        const int b = (kw << 4) + (rg << 2) + r;
        out[((size_t)b * SEQ + t) * HD + j0 + u_] = hsv[r];
        if (t == SEQ - 1) {
          out[OUT_H + (size_t)(b << 10) + j0 + u_] = hsv[r];
          out[OUT_C + (size_t)(b << 10) + j0 + u_] = csv[r];
        }
      }
    }

    // layer leader: gather 127 peer WGs' 4 flag words each, publish epoch
    if (tl == 0) {
      __syncthreads();
      if (tid >= 1 && tid < 128) {
        const unsigned* pf = bar + (((layer << 7) + tid) << 5);
        while (true) {
          const unsigned f0 = __hip_atomic_load(pf + 0, __ATOMIC_RELAXED, __HIP_MEMORY_SCOPE_AGENT);
          const unsigned f1 = __hip_atomic_load(pf + 1, __ATOMIC_RELAXED, __HIP_MEMORY_SCOPE_AGENT);
          const unsigned f2 = __hip_atomic_load(pf + 2, __ATOMIC_RELAXED, __HIP_MEMORY_SCOPE_AGENT);
          const unsigned f3 = __hip_atomic_load(pf + 3, __ATOMIC_RELAXED, __HIP_MEMORY_SCOPE_AGENT);
          if (f0 >= e && f1 >= e && f2 >= e && f3 >= e) break;
          __builtin_amdgcn_s_sleep(1);
        }
      }
      __syncthreads();
      if (tid == 0)
        __hip_atomic_store(layer ? go1 : go0, e, __ATOMIC_RELAXED, __HIP_MEMORY_SCOPE_AGENT);
    }

    if ((t & 15) == 15) __builtin_amdgcn_fence(__ATOMIC_ACQUIRE, "agent");
  }
}

// prep: combined bias, zero h-ring slot 31 (both packed buffers), flags
__global__ void lstm_prep(const float* __restrict__ bih, const float* __restrict__ bhh,
                          float* __restrict__ bias,
                          unsigned short* __restrict__ h0p, unsigned short* __restrict__ h1p,
                          unsigned* __restrict__ bar) {
  const size_t i0 = (size_t)blockIdx.x * blockDim.x + threadIdx.x;
  const size_t stride = (size_t)gridDim.x * blockDim.x;
  for (size_t idx = i0; idx < 8192; idx += stride) bias[idx] = bih[idx] + bhh[idx];
  const ushort4 z = make_ushort4(0, 0, 0, 0);
  const size_t so = ((size_t)RMASK * HSLOT) >> 2;  // slot 31 base, ushort4 units
  for (size_t idx = i0; idx < 32768; idx += stride) {
    ((ushort4*)h0p)[so + idx] = z;
    ((ushort4*)h1p)[so + idx] = z;
  }
  for (size_t idx = i0; idx < 8256; idx += stride) bar[idx] = 0u;
}

extern "C" void kernel_launch(void* const* d_in, const int* in_sizes, int n_in,
                              void* d_out, int out_size, void* d_ws, size_t ws_size,
                              hipStream_t stream) {
  const float* x     = (const float*)d_in[0];
  const float* Wih_f = (const float*)d_in[1];
  const float* bih   = (const float*)d_in[2];
  const float* Whh_f = (const float*)d_in[3];
  const float* bhh   = (const float*)d_in[4];
  float* out = (float*)d_out;

  char* ws = (char*)d_ws;                                  // ~17 MB used
  float* bias           = (float*)(ws);                    // 32 KB
  unsigned* bar         = (unsigned*)(ws + 65536);         // flags + epochs
  unsigned short* h0p   = (unsigned short*)(ws + (1ull << 20));            // 8 MB
  unsigned short* h1p   = (unsigned short*)(ws + (1ull << 20) + (8ull << 20)); // 8 MB

  hipLaunchKernelGGL(lstm_prep, dim3(256), dim3(256), 0, stream,
                     bih, bhh, bias, h0p, h1p, bar);

  hipLaunchKernelGGL(lstm_main, dim3(NWG), dim3(TPB), 0, stream,
                     x, Wih_f, Whh_f, bias, h0p, h1p, out, bar);
}